// Round 1
// baseline (282.085 us; speedup 1.0000x reference)
//
#include <hip/hip_runtime.h>
#include <hip/hip_bf16.h>
#include <stdint.h>

#define BB 4
#define SS 4096
#define HH 768
#define DD 64

typedef __attribute__((ext_vector_type(8))) short bf16x8;
typedef __attribute__((ext_vector_type(4))) short bf16x4;
typedef __attribute__((ext_vector_type(4))) float f32x4;

__device__ __forceinline__ short f2bf(float f) {
  uint32_t u = __builtin_bit_cast(uint32_t, f);
  u += 0x7fffu + ((u >> 16) & 1u);
  return (short)(u >> 16);
}

// ---------------- kernel 0: weight prep (transpose + bf16 + fold qk scale) ---
__global__ __launch_bounds__(256) void prep_kernel(
    const float* __restrict__ Wq, const float* __restrict__ bq,
    const float* __restrict__ Wk, const float* __restrict__ bk,
    const float* __restrict__ Wv, const float* __restrict__ bv,
    const float* __restrict__ Wo,
    short* __restrict__ wqkvT, float* __restrict__ bqkv,
    short* __restrict__ woT) {
  int idx = blockIdx.x * 256 + threadIdx.x;
  const int N1 = 192 * HH;   // wqkvT elements
  const int N2 = HH * DD;    // woT elements
  if (idx < N1) {
    int n = idx / HH, k = idx % HH;
    float v;
    if (n < 64)       v = Wq[k * 64 + n] * 0.125f;   // fold 1/sqrt(64)
    else if (n < 128) v = Wk[k * 64 + (n - 64)];
    else              v = Wv[k * 64 + (n - 128)];
    wqkvT[idx] = f2bf(v);
  } else if (idx < N1 + N2) {
    int j = idx - N1;
    int n = j / 64, k = j % 64;
    woT[j] = f2bf(Wo[k * HH + n]);
  } else if (idx < N1 + N2 + 192) {
    int n = idx - N1 - N2;
    float v;
    if (n < 64)       v = bq[n] * 0.125f;
    else if (n < 128) v = bk[n - 64];
    else              v = bv[n - 128];
    bqkv[n] = v;
  }
}

// ---------------- kernel 1: QKV projection ----------------------------------
// C[16384, 192] = x[16384, 768] @ Wqkv ; q,k stored [s][64] bf16, v stored
// transposed [64][s] bf16 per batch. 64 rows/block, grid 256.
__global__ __launch_bounds__(256) void qkv_kernel(
    const float* __restrict__ x, const short* __restrict__ wT,
    const float* __restrict__ bqkv,
    short* __restrict__ qb, short* __restrict__ kb, short* __restrict__ vT) {
  __shared__ short xa[64 * 72];     // A tile, pad 72 -> 2-way bank alias only
  __shared__ short wt[192 * 72];    // B tile (rows = output col n, 64 k)
  const int tid = threadIdx.x;
  const int w = tid >> 6, lane = tid & 63, g = lane >> 4, n16 = lane & 15;
  const int m0 = blockIdx.x * 64;

  f32x4 acc[12] = {};

  for (int kc = 0; kc < 12; ++kc) {
    __syncthreads();
    // stage x tile 64x64 fp32 -> bf16 (1024 float4 chunks, 4/thread)
    for (int i = 0; i < 4; ++i) {
      int c = tid + 256 * i;
      int row = c >> 4, fo = (c & 15) * 4;
      const float4 f = *(const float4*)&x[(m0 + row) * HH + kc * 64 + fo];
      bf16x4 p = { f2bf(f.x), f2bf(f.y), f2bf(f.z), f2bf(f.w) };
      *(bf16x4*)&xa[row * 72 + fo] = p;
    }
    // stage wT tile 192x64 bf16 (1536 b128 chunks, 6/thread)
    for (int i = 0; i < 6; ++i) {
      int c = tid + 256 * i;
      int row = c >> 3, off = (c & 7) * 8;
      *(bf16x8*)&wt[row * 72 + off] =
          *(const bf16x8*)&wT[row * HH + kc * 64 + off];
    }
    __syncthreads();
#pragma unroll
    for (int kk = 0; kk < 2; ++kk) {
      const int ko = kk * 32 + g * 8;
      bf16x8 af = *(const bf16x8*)&xa[(w * 16 + n16) * 72 + ko];
#pragma unroll
      for (int ct = 0; ct < 12; ++ct) {
        bf16x8 bfr = *(const bf16x8*)&wt[(ct * 16 + n16) * 72 + ko];
        acc[ct] = __builtin_amdgcn_mfma_f32_16x16x32_bf16(af, bfr, acc[ct], 0, 0, 0);
      }
    }
  }
  // epilogue: C layout col=lane&15, row=4*(lane>>4)+r
#pragma unroll
  for (int ct = 0; ct < 12; ++ct) {
    int nG = ct * 16 + n16;
    float bias = bqkv[nG];
#pragma unroll
    for (int r = 0; r < 4; ++r) {
      int rowg = m0 + w * 16 + g * 4 + r;
      short val = f2bf(acc[ct][r] + bias);
      if (nG < 64) {
        qb[rowg * 64 + nG] = val;
      } else if (nG < 128) {
        kb[rowg * 64 + (nG - 64)] = val;
      } else {
        int b = rowg >> 12, s = rowg & 4095;
        vT[(b * 64 + (nG - 128)) * SS + s] = val;
      }
    }
  }
}

// ---------------- kernel 2: flash attention ---------------------------------
// grid = 4 batches x 64 q-tiles (64 rows). wave w owns 16 q rows.
// k-loop: 32 tiles of 128 keys.
__global__ __launch_bounds__(256) void flash_kernel(
    const short* __restrict__ qb, const short* __restrict__ kb,
    const short* __restrict__ vT, short* __restrict__ ctx) {
  __shared__ short kt_lds[128 * 72];      // K tile [kv row][d], pad 72
  __shared__ short vt_lds[64 * 136];      // V^T tile [d][kv], pad 136
  __shared__ short p_lds[4 * 16 * 136];   // per-wave P (C->A layout transform)
  const int tid = threadIdx.x;
  const int w = tid >> 6, lane = tid & 63, g = lane >> 4, n16 = lane & 15;
  const int b = blockIdx.x >> 6, qt = blockIdx.x & 63;
  const short* qB = qb + (b * SS + qt * 64) * DD;
  const short* kB = kb + b * SS * DD;
  const short* vB = vT + b * DD * SS;

  // Q A-fragments direct from global, held for whole loop (q pre-scaled)
  bf16x8 aQ[2];
#pragma unroll
  for (int kk = 0; kk < 2; ++kk)
    aQ[kk] = *(const bf16x8*)&qB[(w * 16 + n16) * DD + kk * 32 + g * 8];

  f32x4 oacc[4] = {};
  float m_run[4], l_run[4];
#pragma unroll
  for (int r = 0; r < 4; ++r) { m_run[r] = -__builtin_inff(); l_run[r] = 0.f; }

  short* pw = &p_lds[w * 16 * 136];

  for (int kt = 0; kt < 32; ++kt) {
    __syncthreads();
    // stage K tile: 128 rows x 64 bf16 (4 b128 chunks/thread)
    for (int i = 0; i < 4; ++i) {
      int c = tid + 256 * i;
      int row = c >> 3, off = (c & 7) * 8;
      *(bf16x8*)&kt_lds[row * 72 + off] =
          *(const bf16x8*)&kB[(kt * 128 + row) * DD + off];
    }
    // stage V^T tile: 64 rows x 128 bf16 (4 b128 chunks/thread)
    for (int i = 0; i < 4; ++i) {
      int c = tid + 256 * i;
      int row = c >> 4, off = (c & 15) * 8;
      *(bf16x8*)&vt_lds[row * 136 + off] =
          *(const bf16x8*)&vB[row * SS + kt * 128 + off];
    }
    __syncthreads();

    // S = Q K^T : wave's 16 rows x 128 cols
    f32x4 sacc[8] = {};
#pragma unroll
    for (int kk = 0; kk < 2; ++kk) {
      const int ko = kk * 32 + g * 8;
#pragma unroll
      for (int ct = 0; ct < 8; ++ct) {
        bf16x8 bK = *(const bf16x8*)&kt_lds[(ct * 16 + n16) * 72 + ko];
        sacc[ct] = __builtin_amdgcn_mfma_f32_16x16x32_bf16(aQ[kk], bK, sacc[ct], 0, 0, 0);
      }
    }

    // online softmax per row (lane holds rows 4g+r, cols n16+16ct)
#pragma unroll
    for (int r = 0; r < 4; ++r) {
      float mx = sacc[0][r];
#pragma unroll
      for (int ct = 1; ct < 8; ++ct) mx = fmaxf(mx, sacc[ct][r]);
#pragma unroll
      for (int d = 1; d < 16; d <<= 1) mx = fmaxf(mx, __shfl_xor(mx, d));
      float newm = fmaxf(m_run[r], mx);
      float alpha = __expf(m_run[r] - newm);
      m_run[r] = newm;
      float rs = 0.f;
#pragma unroll
      for (int ct = 0; ct < 8; ++ct) {
        float p = __expf(sacc[ct][r] - newm);
        sacc[ct][r] = p;
        rs += p;
      }
#pragma unroll
      for (int d = 1; d < 16; d <<= 1) rs += __shfl_xor(rs, d);
      l_run[r] = l_run[r] * alpha + rs;
#pragma unroll
      for (int dt = 0; dt < 4; ++dt) oacc[dt][r] *= alpha;
    }

    // P: C layout -> A layout via per-wave LDS
#pragma unroll
    for (int ct = 0; ct < 8; ++ct)
#pragma unroll
      for (int r = 0; r < 4; ++r)
        pw[(g * 4 + r) * 136 + ct * 16 + n16] = f2bf(sacc[ct][r]);
    __syncthreads();

    // O += P V
#pragma unroll
    for (int kk = 0; kk < 4; ++kk) {
      const int ko = kk * 32 + g * 8;
      bf16x8 aP = *(const bf16x8*)&pw[n16 * 136 + ko];
#pragma unroll
      for (int dt = 0; dt < 4; ++dt) {
        bf16x8 bV = *(const bf16x8*)&vt_lds[(dt * 16 + n16) * 136 + ko];
        oacc[dt] = __builtin_amdgcn_mfma_f32_16x16x32_bf16(aP, bV, oacc[dt], 0, 0, 0);
      }
    }
  }

  // epilogue: ctx = O / l, bf16 [s][64]
#pragma unroll
  for (int r = 0; r < 4; ++r) {
    float inv = 1.f / l_run[r];
    int sq = qt * 64 + w * 16 + g * 4 + r;
#pragma unroll
    for (int dt = 0; dt < 4; ++dt)
      ctx[(b * SS + sq) * DD + dt * 16 + n16] = f2bf(oacc[dt][r] * inv);
  }
}

// ---------------- kernel 3: output projection -------------------------------
// out[16384, 768] = ctx[16384, 64] @ Wo + bo, fp32 out.
// grid: (256 row-blocks of 64) x (3 col-blocks of 256)
__global__ __launch_bounds__(256) void proj_kernel(
    const short* __restrict__ ctx, const short* __restrict__ woT,
    const float* __restrict__ bo, float* __restrict__ out) {
  __shared__ short ca[64 * 72];
  __shared__ short wo[256 * 72];
  const int tid = threadIdx.x;
  const int w = tid >> 6, lane = tid & 63, g = lane >> 4, n16 = lane & 15;
  const int m0 = blockIdx.x * 64;
  const int n0 = blockIdx.y * 256;

  for (int i = 0; i < 2; ++i) {
    int c = tid + 256 * i;
    int row = c >> 3, off = (c & 7) * 8;
    *(bf16x8*)&ca[row * 72 + off] = *(const bf16x8*)&ctx[(m0 + row) * DD + off];
  }
  for (int i = 0; i < 8; ++i) {
    int c = tid + 256 * i;
    int row = c >> 3, off = (c & 7) * 8;
    *(bf16x8*)&wo[row * 72 + off] = *(const bf16x8*)&woT[(n0 + row) * DD + off];
  }
  __syncthreads();

  f32x4 acc[16] = {};
#pragma unroll
  for (int kk = 0; kk < 2; ++kk) {
    const int ko = kk * 32 + g * 8;
    bf16x8 aC = *(const bf16x8*)&ca[(w * 16 + n16) * 72 + ko];
#pragma unroll
    for (int ct = 0; ct < 16; ++ct) {
      bf16x8 bW = *(const bf16x8*)&wo[(ct * 16 + n16) * 72 + ko];
      acc[ct] = __builtin_amdgcn_mfma_f32_16x16x32_bf16(aC, bW, acc[ct], 0, 0, 0);
    }
  }
#pragma unroll
  for (int ct = 0; ct < 16; ++ct) {
    int nG = n0 + ct * 16 + n16;
    float bias = bo[nG];
#pragma unroll
    for (int r = 0; r < 4; ++r) {
      int rowg = m0 + w * 16 + g * 4 + r;
      out[rowg * HH + nG] = acc[ct][r] + bias;
    }
  }
}

// ---------------- launch ----------------------------------------------------
extern "C" void kernel_launch(void* const* d_in, const int* in_sizes, int n_in,
                              void* d_out, int out_size, void* d_ws, size_t ws_size,
                              hipStream_t stream) {
  const float* x  = (const float*)d_in[0];
  const float* Wq = (const float*)d_in[1];
  const float* bq = (const float*)d_in[2];
  const float* Wk = (const float*)d_in[3];
  const float* bk = (const float*)d_in[4];
  const float* Wv = (const float*)d_in[5];
  const float* bv = (const float*)d_in[6];
  const float* Wo = (const float*)d_in[7];
  const float* bo = (const float*)d_in[8];
  float* out = (float*)d_out;

  char* ws = (char*)d_ws;
  short* qb    = (short*)(ws + 0);                         // 2 MB
  short* kb    = (short*)(ws + (2u << 20));                // 2 MB
  short* vT    = (short*)(ws + (4u << 20));                // 2 MB  [b][64][4096]
  short* ctx   = (short*)(ws + (6u << 20));                // 2 MB
  short* wqkvT = (short*)(ws + (8u << 20));                // 288 KB [192][768]
  short* woT   = (short*)(ws + (8u << 20) + 384 * 1024);   // 96 KB  [768][64]
  float* bqkv  = (float*)(ws + (8u << 20) + 512 * 1024);   // 768 B

  hipLaunchKernelGGL(prep_kernel, dim3(769), dim3(256), 0, stream,
                     Wq, bq, Wk, bk, Wv, bv, Wo, wqkvT, bqkv, woT);
  hipLaunchKernelGGL(qkv_kernel, dim3(256), dim3(256), 0, stream,
                     x, wqkvT, bqkv, qb, kb, vT);
  hipLaunchKernelGGL(flash_kernel, dim3(256), dim3(256), 0, stream,
                     qb, kb, vT, ctx);
  hipLaunchKernelGGL(proj_kernel, dim3(256, 3), dim3(256), 0, stream,
                     ctx, woT, bo, out);
}

// Round 2
// 245.542 us; speedup vs baseline: 1.1488x; 1.1488x over previous
//
#include <hip/hip_runtime.h>
#include <hip/hip_bf16.h>
#include <stdint.h>

#define BB 4
#define SS 4096
#define HH 768
#define DD 64

typedef __attribute__((ext_vector_type(8))) short bf16x8;
typedef __attribute__((ext_vector_type(4))) short bf16x4;
typedef __attribute__((ext_vector_type(4))) float f32x4;

__device__ __forceinline__ short f2bf(float f) {
  uint32_t u = __builtin_bit_cast(uint32_t, f);
  u += 0x7fffu + ((u >> 16) & 1u);
  return (short)(u >> 16);
}

// scale = 1/sqrt(64) * log2(e): softmax done in base-2 (v_exp_f32 native)
#define QSCALE 0.18033688011112042f

// ---------------- kernel 0: weight prep -------------------------------------
__global__ __launch_bounds__(256) void prep_kernel(
    const float* __restrict__ Wq, const float* __restrict__ bq,
    const float* __restrict__ Wk, const float* __restrict__ bk,
    const float* __restrict__ Wv, const float* __restrict__ bv,
    const float* __restrict__ Wo,
    short* __restrict__ wqkvT, float* __restrict__ bqkv,
    short* __restrict__ woT) {
  int idx = blockIdx.x * 256 + threadIdx.x;
  const int N1 = 192 * HH;
  const int N2 = HH * DD;
  if (idx < N1) {
    int n = idx / HH, k = idx % HH;
    float v;
    if (n < 64)       v = Wq[k * 64 + n] * QSCALE;
    else if (n < 128) v = Wk[k * 64 + (n - 64)];
    else              v = Wv[k * 64 + (n - 128)];
    wqkvT[idx] = f2bf(v);
  } else if (idx < N1 + N2) {
    int j = idx - N1;
    int n = j / 64, k = j % 64;
    woT[j] = f2bf(Wo[k * HH + n]);
  } else if (idx < N1 + N2 + 192) {
    int n = idx - N1 - N2;
    float v;
    if (n < 64)       v = bq[n] * QSCALE;
    else if (n < 128) v = bk[n - 64];
    else              v = bv[n - 128];
    bqkv[n] = v;
  }
}

// ---------------- kernel 1: QKV projection (barrier-free) -------------------
// grid 1024: block = 16 rows; wave w = cols w*48..w*48+48. No LDS.
__global__ __launch_bounds__(256, 4) void qkv_kernel(
    const float* __restrict__ x, const short* __restrict__ wT,
    const float* __restrict__ bqkv,
    short* __restrict__ qb, short* __restrict__ kb, short* __restrict__ vT) {
  const int tid = threadIdx.x;
  const int w = tid >> 6, lane = tid & 63, g = lane >> 4, n16 = lane & 15;
  const int m0 = blockIdx.x * 16;
  const int colbase = w * 48;

  f32x4 acc[3] = {};
  const float* xr = &x[(m0 + n16) * HH];
  const short* wr0 = &wT[(colbase + n16) * HH];
  const short* wr1 = &wT[(colbase + 16 + n16) * HH];
  const short* wr2 = &wT[(colbase + 32 + n16) * HH];

#pragma unroll 2
  for (int kc = 0; kc < 24; ++kc) {
    const int ko = kc * 32 + g * 8;
    const float4 f0 = *(const float4*)&xr[ko];
    const float4 f1 = *(const float4*)&xr[ko + 4];
    bf16x8 af = { f2bf(f0.x), f2bf(f0.y), f2bf(f0.z), f2bf(f0.w),
                  f2bf(f1.x), f2bf(f1.y), f2bf(f1.z), f2bf(f1.w) };
    bf16x8 b0 = *(const bf16x8*)&wr0[ko];
    bf16x8 b1 = *(const bf16x8*)&wr1[ko];
    bf16x8 b2 = *(const bf16x8*)&wr2[ko];
    acc[0] = __builtin_amdgcn_mfma_f32_16x16x32_bf16(af, b0, acc[0], 0, 0, 0);
    acc[1] = __builtin_amdgcn_mfma_f32_16x16x32_bf16(af, b1, acc[1], 0, 0, 0);
    acc[2] = __builtin_amdgcn_mfma_f32_16x16x32_bf16(af, b2, acc[2], 0, 0, 0);
  }

#pragma unroll
  for (int ct = 0; ct < 3; ++ct) {
    int nG = colbase + ct * 16 + n16;
    float bias = bqkv[nG];
#pragma unroll
    for (int r = 0; r < 4; ++r) {
      int rowg = m0 + g * 4 + r;
      short val = f2bf(acc[ct][r] + bias);
      if (nG < 64) {
        qb[rowg * 64 + nG] = val;
      } else if (nG < 128) {
        kb[rowg * 64 + (nG - 64)] = val;
      } else {
        int b = rowg >> 12, s = rowg & 4095;
        vT[(b * 64 + (nG - 128)) * SS + s] = val;
      }
    }
  }
}

// ---------------- kernel 2: flash attention, split-K x4 ---------------------
// grid 1024: blockIdx = rg*4+sp; rg = 64-q-row group, sp = 1024-key split.
// K staged in LDS (shared by 4 waves); V B-frags direct from global (L1-hot);
// P transform per-wave LDS stride 132 (bank-clean). Partials to Opart/ml.
__global__ __launch_bounds__(256, 4) void flash_kernel(
    const short* __restrict__ qb, const short* __restrict__ kb,
    const short* __restrict__ vT,
    float* __restrict__ Opart, float* __restrict__ ml) {
  __shared__ short kt_lds[128 * 72];      // K tile [key][d]
  __shared__ short p_lds[4 * 16 * 132];   // per-wave P, stride 132
  const int tid = threadIdx.x;
  const int w = tid >> 6, lane = tid & 63, g = lane >> 4, n16 = lane & 15;
  const int rg = blockIdx.x >> 2, sp = blockIdx.x & 3;
  const int b = rg >> 6, qt = rg & 63;
  const short* qB = qb + (b * SS + qt * 64) * DD;
  const short* kB = kb + (b * SS + sp * 1024) * DD;
  const short* vB = vT + b * DD * SS + sp * 1024;

  bf16x8 aQ[2];
#pragma unroll
  for (int kk = 0; kk < 2; ++kk)
    aQ[kk] = *(const bf16x8*)&qB[(w * 16 + n16) * DD + kk * 32 + g * 8];

  f32x4 oacc[4] = {};
  float m_run[4], l_run[4];
#pragma unroll
  for (int r = 0; r < 4; ++r) { m_run[r] = -__builtin_inff(); l_run[r] = 0.f; }

  short* pw = &p_lds[w * 16 * 132];

  for (int kt = 0; kt < 8; ++kt) {
    __syncthreads();
    // stage K tile: 128 x 64 bf16, 4 b128 chunks per thread
#pragma unroll
    for (int i = 0; i < 4; ++i) {
      int c = tid + 256 * i;
      int row = c >> 3, off = (c & 7) * 8;
      *(bf16x8*)&kt_lds[row * 72 + off] =
          *(const bf16x8*)&kB[(kt * 128 + row) * DD + off];
    }
    __syncthreads();

    // S = Q K^T
    f32x4 sacc[8] = {};
#pragma unroll
    for (int kk = 0; kk < 2; ++kk) {
      const int ko = kk * 32 + g * 8;
#pragma unroll
      for (int ct = 0; ct < 8; ++ct) {
        bf16x8 bK = *(const bf16x8*)&kt_lds[(ct * 16 + n16) * 72 + ko];
        sacc[ct] = __builtin_amdgcn_mfma_f32_16x16x32_bf16(aQ[kk], bK, sacc[ct], 0, 0, 0);
      }
    }

    // online softmax, base-2 domain (scale*log2e folded into Wq)
#pragma unroll
    for (int r = 0; r < 4; ++r) {
      float mx = sacc[0][r];
#pragma unroll
      for (int ct = 1; ct < 8; ++ct) mx = fmaxf(mx, sacc[ct][r]);
#pragma unroll
      for (int d = 1; d < 16; d <<= 1) mx = fmaxf(mx, __shfl_xor(mx, d));
      float newm = fmaxf(m_run[r], mx);
      float alpha = __builtin_amdgcn_exp2f(m_run[r] - newm);
      m_run[r] = newm;
      float rs = 0.f;
#pragma unroll
      for (int ct = 0; ct < 8; ++ct) {
        float p = __builtin_amdgcn_exp2f(sacc[ct][r] - newm);
        sacc[ct][r] = p;
        rs += p;
      }
#pragma unroll
      for (int d = 1; d < 16; d <<= 1) rs += __shfl_xor(rs, d);
      l_run[r] = l_run[r] * alpha + rs;
#pragma unroll
      for (int dt = 0; dt < 4; ++dt) oacc[dt][r] *= alpha;
    }

    // P: C layout -> A layout, per-wave LDS (no barrier)
#pragma unroll
    for (int ct = 0; ct < 8; ++ct)
#pragma unroll
      for (int r = 0; r < 4; ++r)
        pw[(g * 4 + r) * 132 + ct * 16 + n16] = f2bf(sacc[ct][r]);

    // O += P V  (V fragments straight from global, identical across waves)
#pragma unroll
    for (int kk = 0; kk < 4; ++kk) {
      const int ko = kk * 32 + g * 8;
      bf16x4 plo = *(const bf16x4*)&pw[n16 * 132 + ko];
      bf16x4 phi = *(const bf16x4*)&pw[n16 * 132 + ko + 4];
      bf16x8 aP = __builtin_shufflevector(plo, phi, 0, 1, 2, 3, 4, 5, 6, 7);
#pragma unroll
      for (int dt = 0; dt < 4; ++dt) {
        bf16x8 bV = *(const bf16x8*)&vB[(dt * 16 + n16) * SS + kt * 128 + ko];
        oacc[dt] = __builtin_amdgcn_mfma_f32_16x16x32_bf16(aP, bV, oacc[dt], 0, 0, 0);
      }
    }
  }

  // epilogue: write partials (O fp32, m, l)
  const int part = blockIdx.x;
#pragma unroll
  for (int r = 0; r < 4; ++r) {
    int row = w * 16 + g * 4 + r;
#pragma unroll
    for (int dt = 0; dt < 4; ++dt)
      Opart[(part * 64 + row) * 64 + dt * 16 + n16] = oacc[dt][r];
  }
  if (n16 == 0) {
#pragma unroll
    for (int r = 0; r < 4; ++r) {
      int row = w * 16 + g * 4 + r;
      ml[(part * 64 + row) * 2]     = m_run[r];
      ml[(part * 64 + row) * 2 + 1] = l_run[r];
    }
  }
}

// ---------------- kernel 2b: merge split-K partials -------------------------
// grid 1024 x 256: thread -> (q row, 4 d-values)
__global__ __launch_bounds__(256) void merge_kernel(
    const float* __restrict__ Opart, const float* __restrict__ ml,
    short* __restrict__ ctx) {
  int t = blockIdx.x * 256 + threadIdx.x;
  int q = t >> 4, dq = (t & 15) * 4;
  int rg = q >> 6, r64 = q & 63;
  float m[4], l[4];
#pragma unroll
  for (int sp = 0; sp < 4; ++sp) {
    m[sp] = ml[((rg * 4 + sp) * 64 + r64) * 2];
    l[sp] = ml[((rg * 4 + sp) * 64 + r64) * 2 + 1];
  }
  float M = fmaxf(fmaxf(m[0], m[1]), fmaxf(m[2], m[3]));
  float wgt[4], lt = 0.f;
#pragma unroll
  for (int sp = 0; sp < 4; ++sp) {
    wgt[sp] = __builtin_amdgcn_exp2f(m[sp] - M);
    lt += wgt[sp] * l[sp];
  }
  float inv = 1.f / lt;
  float o0 = 0.f, o1 = 0.f, o2 = 0.f, o3 = 0.f;
#pragma unroll
  for (int sp = 0; sp < 4; ++sp) {
    const float4 v = *(const float4*)&Opart[((rg * 4 + sp) * 64 + r64) * 64 + dq];
    o0 += wgt[sp] * v.x; o1 += wgt[sp] * v.y;
    o2 += wgt[sp] * v.z; o3 += wgt[sp] * v.w;
  }
  bf16x4 res = { f2bf(o0 * inv), f2bf(o1 * inv), f2bf(o2 * inv), f2bf(o3 * inv) };
  *(bf16x4*)&ctx[q * 64 + dq] = res;
}

// ---------------- kernel 3: output projection (barrier-free) ----------------
// grid 1024: block = 16 rows; wave w = cols w*192..+192. No LDS.
__global__ __launch_bounds__(256, 4) void proj_kernel(
    const short* __restrict__ ctx, const short* __restrict__ woT,
    const float* __restrict__ bo, float* __restrict__ out) {
  const int tid = threadIdx.x;
  const int w = tid >> 6, lane = tid & 63, g = lane >> 4, n16 = lane & 15;
  const int m0 = blockIdx.x * 16;
  const int colbase = w * 192;

  f32x4 acc[12] = {};
#pragma unroll
  for (int kk = 0; kk < 2; ++kk) {
    const int ko = kk * 32 + g * 8;
    bf16x8 aC = *(const bf16x8*)&ctx[(m0 + n16) * DD + ko];
#pragma unroll
    for (int ct = 0; ct < 12; ++ct) {
      bf16x8 bW = *(const bf16x8*)&woT[(colbase + ct * 16 + n16) * DD + ko];
      acc[ct] = __builtin_amdgcn_mfma_f32_16x16x32_bf16(aC, bW, acc[ct], 0, 0, 0);
    }
  }
#pragma unroll
  for (int ct = 0; ct < 12; ++ct) {
    int nG = colbase + ct * 16 + n16;
    float bias = bo[nG];
#pragma unroll
    for (int r = 0; r < 4; ++r) {
      int rowg = m0 + g * 4 + r;
      out[rowg * HH + nG] = acc[ct][r] + bias;
    }
  }
}

// ---------------- launch ----------------------------------------------------
extern "C" void kernel_launch(void* const* d_in, const int* in_sizes, int n_in,
                              void* d_out, int out_size, void* d_ws, size_t ws_size,
                              hipStream_t stream) {
  const float* x  = (const float*)d_in[0];
  const float* Wq = (const float*)d_in[1];
  const float* bq = (const float*)d_in[2];
  const float* Wk = (const float*)d_in[3];
  const float* bk = (const float*)d_in[4];
  const float* Wv = (const float*)d_in[5];
  const float* bv = (const float*)d_in[6];
  const float* Wo = (const float*)d_in[7];
  const float* bo = (const float*)d_in[8];
  float* out = (float*)d_out;

  char* ws = (char*)d_ws;
  short* qb    = (short*)(ws + 0);                          // 2 MB
  short* kb    = (short*)(ws + (2u << 20));                 // 2 MB
  short* vT    = (short*)(ws + (4u << 20));                 // 2 MB [b][64][4096]
  short* ctx   = (short*)(ws + (6u << 20));                 // 2 MB
  short* wqkvT = (short*)(ws + (8u << 20));                 // 288 KB
  short* woT   = (short*)(ws + (8u << 20) + 384 * 1024);    // 96 KB
  float* bqkv  = (float*)(ws + (8u << 20) + 512 * 1024);    // 768 B
  float* ml    = (float*)(ws + (9u << 20));                 // 512 KB
  float* Opart = (float*)(ws + (10u << 20));                // 16.78 MB

  hipLaunchKernelGGL(prep_kernel, dim3(769), dim3(256), 0, stream,
                     Wq, bq, Wk, bk, Wv, bv, Wo, wqkvT, bqkv, woT);
  hipLaunchKernelGGL(qkv_kernel, dim3(1024), dim3(256), 0, stream,
                     x, wqkvT, bqkv, qb, kb, vT);
  hipLaunchKernelGGL(flash_kernel, dim3(1024), dim3(256), 0, stream,
                     qb, kb, vT, Opart, ml);
  hipLaunchKernelGGL(merge_kernel, dim3(1024), dim3(256), 0, stream,
                     Opart, ml, ctx);
  hipLaunchKernelGGL(proj_kernel, dim3(1024), dim3(256), 0, stream,
                     ctx, woT, bo, out);
}